// Round 2
// 362.387 us; speedup vs baseline: 1.0505x; 1.0505x over previous
//
#include <hip/hip_runtime.h>
#include <hip/hip_bf16.h>
#include <stdint.h>

// B=4, T=256, U=64, D=512, H=512, V=1024
// gemm2: M=65536, K=512, N=1024 -> 68.7 GFLOP, out 268 MB fp32

typedef __bf16 bf16_t;
typedef bf16_t bf16x8 __attribute__((ext_vector_type(8)));
typedef float f32x4 __attribute__((ext_vector_type(4)));
typedef unsigned short u16x8 __attribute__((ext_vector_type(8)));

#define GLD16(gp, lp)                                                          \
  __builtin_amdgcn_global_load_lds(                                            \
      (const __attribute__((address_space(1))) void*)(gp),                     \
      (__attribute__((address_space(3))) void*)(lp), 16, 0, 0)

__device__ __forceinline__ unsigned short f2bf(float f) {
  unsigned int u = __float_as_uint(f);
  return (unsigned short)((u + 0x7FFFu + ((u >> 16) & 1u)) >> 16);
}

// gelu(x) = x * sigmoid(1.5957691216x + 0.0713548136x^3)  (tanh-approx form)
__device__ __forceinline__ float gelu_f(float x) {
  float t = 1.5957691216057308f * x + 0.07135481283867141f * (x * x * x);
  float e = __expf(-t);
  return x * __builtin_amdgcn_rcpf(1.0f + e);
}

// ---------------------------------------------------------------------------
// prep: fp32 -> bf16. Regions (ushort units):
//   [0,524288) enc | [524288,655360) dec | [655360,917504) w_enc |
//   [917504,1179648) w_dec | [1179648,1703936) w2
// ---------------------------------------------------------------------------
__global__ __launch_bounds__(256) void prep_kernel(
    const float* __restrict__ enc, const float* __restrict__ dec,
    const float* __restrict__ w1, const float* __restrict__ w2,
    unsigned short* __restrict__ o) {
  int i = (blockIdx.x * 256 + threadIdx.x) * 4;
  float4 v;
  if (i < 524288) {
    v = *(const float4*)(enc + i);
  } else if (i < 655360) {
    v = *(const float4*)(dec + (i - 524288));
  } else if (i < 917504) {
    int j = i - 655360;
    v = *(const float4*)(w1 + (j >> 9) * 1024 + (j & 511));
  } else if (i < 1179648) {
    int j = i - 917504;
    v = *(const float4*)(w1 + (j >> 9) * 1024 + 512 + (j & 511));
  } else {
    v = *(const float4*)(w2 + (i - 1179648));
  }
  ushort4 r;
  r.x = f2bf(v.x); r.y = f2bf(v.y); r.z = f2bf(v.z); r.w = f2bf(v.w);
  *(ushort4*)(o + i) = r;
}

// ---------------------------------------------------------------------------
// hidden: bf16 hid[m][h] = gelu(ep[m>>6][h] + dp[dr(m)][h] + b1[h])
// ---------------------------------------------------------------------------
__global__ __launch_bounds__(256) void hidden_kernel(
    const float* __restrict__ ep, const float* __restrict__ dp,
    const float* __restrict__ b1, unsigned short* __restrict__ o) {
  int g = blockIdx.x * 256 + threadIdx.x;
  int m = g >> 6;
  int h = (g & 63) << 3;
  int er = m >> 6;
  int dr = ((m >> 14) << 6) | (m & 63);
  float4 e0 = *(const float4*)(ep + er * 512 + h);
  float4 e1 = *(const float4*)(ep + er * 512 + h + 4);
  float4 d0 = *(const float4*)(dp + dr * 512 + h);
  float4 d1 = *(const float4*)(dp + dr * 512 + h + 4);
  float4 b0 = *(const float4*)(b1 + h);
  float4 b1v = *(const float4*)(b1 + h + 4);
  u16x8 r;
  r[0] = f2bf(gelu_f(e0.x + d0.x + b0.x));
  r[1] = f2bf(gelu_f(e0.y + d0.y + b0.y));
  r[2] = f2bf(gelu_f(e0.z + d0.z + b0.z));
  r[3] = f2bf(gelu_f(e0.w + d0.w + b0.w));
  r[4] = f2bf(gelu_f(e1.x + d1.x + b1v.x));
  r[5] = f2bf(gelu_f(e1.y + d1.y + b1v.y));
  r[6] = f2bf(gelu_f(e1.z + d1.z + b1v.z));
  r[7] = f2bf(gelu_f(e1.w + d1.w + b1v.w));
  *(u16x8*)(o + (size_t)g * 8) = r;
}

// ---------------------------------------------------------------------------
// gemm_core: 128x128, 256 thr, 2-barrier loop. Kept for the small projections.
// XOR swizzle: row r, matrix chunk c at slot c^(r&7).
// ---------------------------------------------------------------------------
__device__ __forceinline__ void gemm_core(
    const bf16_t* __restrict__ A, const bf16_t* __restrict__ B,
    float* __restrict__ C, int m0, int n0, int N, int K) {
  __shared__ bf16_t sA[128 * 64];
  __shared__ bf16_t sB[128 * 64];

  const int tid = threadIdx.x;
  const int lane = tid & 63;
  const int w = tid >> 6;
  const int wm = (w >> 1) * 64;
  const int wn = (w & 1) * 64;

  const int srow = w * 32 + (lane >> 3);
  const int scol = (((lane & 7) ^ (lane >> 3)) << 3);
  const bf16_t* gA = A + (size_t)(m0 + srow) * K + scol;
  const bf16_t* gB = B + (size_t)(n0 + srow) * K + scol;

  const int rowA = wm + (lane & 15);
  const int rowB = wn + (lane & 15);
  const int sw0 = (lane >> 4) ^ (lane & 7);
  const bf16x8* pA = (const bf16x8*)sA;
  const bf16x8* pB = (const bf16x8*)sB;

  f32x4 acc[4][4] = {};

  for (int kt = 0; kt < K; kt += 64) {
#pragma unroll
    for (int j = 0; j < 4; j++) {
      GLD16(gA + (size_t)(j * 8) * K + kt, sA + (w * 4 + j) * 512);
      GLD16(gB + (size_t)(j * 8) * K + kt, sB + (w * 4 + j) * 512);
    }
    __syncthreads();

#pragma unroll
    for (int kk = 0; kk < 2; kk++) {
      const int sw = sw0 ^ (kk << 2);
      bf16x8 af[4], bb[4];
#pragma unroll
      for (int i = 0; i < 4; i++) af[i] = pA[(rowA + i * 16) * 8 + sw];
#pragma unroll
      for (int j = 0; j < 4; j++) bb[j] = pB[(rowB + j * 16) * 8 + sw];
#pragma unroll
      for (int i = 0; i < 4; i++)
#pragma unroll
        for (int j = 0; j < 4; j++)
          acc[i][j] = __builtin_amdgcn_mfma_f32_16x16x32_bf16(
              af[i], bb[j], acc[i][j], 0, 0, 0);
    }
    __syncthreads();
  }

  const int crow = m0 + wm + (lane >> 4) * 4;
  const int ccol = n0 + wn + (lane & 15);
  float* Cp = C + (size_t)crow * N + ccol;
#pragma unroll
  for (int i = 0; i < 4; i++)
#pragma unroll
    for (int r = 0; r < 4; r++)
#pragma unroll
      for (int j = 0; j < 4; j++)
        Cp[(size_t)(i * 16 + r) * N + j * 16] = acc[i][j][r];
}

// fused projections: y<8 -> enc proj (1024x512), y>=8 -> dec proj (256x512)
__global__ __launch_bounds__(256) void proj_kernel(
    const bf16_t* __restrict__ encA, const bf16_t* __restrict__ wenc,
    float* __restrict__ encC, const bf16_t* __restrict__ decA,
    const bf16_t* __restrict__ wdec, float* __restrict__ decC) {
  int by = blockIdx.y;
  if (by < 8) {
    gemm_core(encA, wenc, encC, by * 128, blockIdx.x * 128, 512, 512);
  } else {
    gemm_core(decA, wdec, decC, (by - 8) * 128, blockIdx.x * 128, 512, 512);
  }
}

// ---------------------------------------------------------------------------
// gemm_big2: 256x256 tile, BK=64, 8 waves (2Mx4N), 8-phase schedule with
// counted vmcnt (T3+T4) + setprio (T5). M=65536 N=1024 K=512 fixed.
// LDS 128 KiB: sA/sB [2 dbuf][256][64] bf16, XOR swizzle slot c^(r&7).
//
// Region/read alignment (race-fix vs r1):
//   sA region RH = rows RH*64+[0,64) of each 128-row band; phase RH reads
//     exactly that set (wave wr reads rows wr*128+RH*64+[0,64)).
//   sB region H  = rows [H*128, H*128+128); phase CH reads exactly region CH
//     (wave wc reads rows wc*32+CH*128+[0,32)) -- B frag cols are two 32-wide
//     stripes per wave: wc*32 and wc*32+128.
//   => no phase stages a region that any same-phase read touches, and every
//   stage issues >=1 full phase (2 barriers) after the last read of the old
//   data in that region (reads drain via lgkmcnt before the phase's MFMAs).
//
// Stage schedule (iter i computes tile 2i from b0, tile 2i+1 from b1):
//   p0: (2i+1).A1->b1   p1: (2i+1).B1->b1   p2: (2i+2).A0->b0
//   p3: (2i+2).B0->b0 VMC4   p4: (2i+2).A1->b0   p5: (2i+2).B1->b0
//   p6: (2i+3).A0->b1   p7: (2i+3).B0->b1 VMC4
// VMC4 @p3: 4 newest = p2+p3 (->b0); all of b1 (tile 2i+1) landed.
// VMC4 @p7: 4 newest = p6+p7 (->b1); all of b0 (tile 2i+2) landed.
// ---------------------------------------------------------------------------

#define STG_A(BUF, RH, KT)                                                     \
  do {                                                                         \
    GLD16(gA + (size_t)((RH) * 64) * 512 + (KT) * 64,                          \
          &sA[BUF][(RH) * 64 + w * 8][0]);                                     \
    GLD16(gA + (size_t)((RH) * 64 + 128) * 512 + (KT) * 64,                    \
          &sA[BUF][(RH) * 64 + 128 + w * 8][0]);                               \
  } while (0)

// B: wave w stages rows H*128 + w*16 + {0,8}; region H = [H*128, H*128+128)
#define STG_B(BUF, H, KT)                                                      \
  do {                                                                         \
    GLD16(gB + (size_t)((H) * 128) * 512 + (KT) * 64,                          \
          &sB[BUF][(H) * 128 + w * 16][0]);                                    \
    GLD16(gB + (size_t)((H) * 128 + 8) * 512 + (KT) * 64,                      \
          &sB[BUF][(H) * 128 + w * 16 + 8][0]);                                \
  } while (0)

#define RD_A(BUF, F, KK)                                                       \
  pA[(BUF) * 2048 + (rowA + (F) * 16) * 8 + (sw0 ^ ((KK) << 2))]
#define RD_B(BUF, ROFF, KK)                                                    \
  pB[(BUF) * 2048 + (rowB + (ROFF)) * 8 + (sw0 ^ ((KK) << 2))]

#define VMC4 asm volatile("s_waitcnt vmcnt(4)" ::: "memory")
#define VMC0 asm volatile("s_waitcnt vmcnt(0)" ::: "memory")
#define NOPX ((void)0)

#define PHASE(BUF, RH, CH, STAGE, VM)                                          \
  do {                                                                         \
    if ((CH) == 0) {                                                           \
      _Pragma("unroll") for (int f = 0; f < 4; f++) {                          \
        af[f][0] = RD_A(BUF, (RH) * 4 + f, 0);                                 \
        af[f][1] = RD_A(BUF, (RH) * 4 + f, 1);                                 \
      }                                                                        \
    }                                                                          \
    _Pragma("unroll") for (int cf = 0; cf < 2; cf++) {                         \
      bb[cf][0] = RD_B(BUF, (CH) * 128 + cf * 16, 0);                          \
      bb[cf][1] = RD_B(BUF, (CH) * 128 + cf * 16, 1);                          \
    }                                                                          \
    STAGE;                                                                     \
    VM;                                                                        \
    __builtin_amdgcn_s_barrier();                                              \
    __builtin_amdgcn_s_setprio(1);                                             \
    _Pragma("unroll") for (int f = 0; f < 4; f++) {                            \
      _Pragma("unroll") for (int cf = 0; cf < 2; cf++) {                       \
        acc[(RH) * 4 + f][(CH) * 2 + cf] =                                     \
            __builtin_amdgcn_mfma_f32_16x16x32_bf16(                           \
                af[f][0], bb[cf][0], acc[(RH) * 4 + f][(CH) * 2 + cf], 0, 0,   \
                0);                                                            \
        acc[(RH) * 4 + f][(CH) * 2 + cf] =                                     \
            __builtin_amdgcn_mfma_f32_16x16x32_bf16(                           \
                af[f][1], bb[cf][1], acc[(RH) * 4 + f][(CH) * 2 + cf], 0, 0,   \
                0);                                                            \
      }                                                                        \
    }                                                                          \
    __builtin_amdgcn_s_setprio(0);                                             \
    __builtin_amdgcn_s_barrier();                                              \
  } while (0)

__global__ __launch_bounds__(512, 2) void gemm_big2(
    const bf16_t* __restrict__ A, const bf16_t* __restrict__ B,
    float* __restrict__ C) {
  __shared__ bf16_t sA[2][256][64];
  __shared__ bf16_t sB[2][256][64];

  const int tid = threadIdx.x;
  const int lane = tid & 63;
  const int w = tid >> 6;
  const int wr = w >> 2;  // 0..1  -> 128-row band
  const int wc = w & 3;   // 0..3  -> two 32-col stripes (wc*32, wc*32+128)

  // bijective XCD-chunked swizzle: 1024 blocks, 128/XCD, n fastest in-chunk
  const int bid = blockIdx.x;
  const int swz = (bid & 7) * 128 + (bid >> 3);
  const int m0 = (swz >> 2) * 256;
  const int n0 = (swz & 3) * 256;

  // staging lane map: lane l -> row +(l>>3), slot l&7 holds chunk
  // (l&7)^(l>>3) == c ^ (row&7)
  const int srowA = w * 8 + (lane >> 3);
  const int srowB = w * 16 + (lane >> 3);
  const int scol = ((lane & 7) ^ (lane >> 3)) << 3;
  const bf16_t* gA = A + (size_t)(m0 + srowA) * 512 + scol;
  const bf16_t* gB = B + (size_t)(n0 + srowB) * 512 + scol;

  // fragment reads: slot = (kk*4 + (lane>>4)) ^ (row&7); row&7 == lane&7
  const int rowA = wr * 128 + (lane & 15);
  const int rowB = wc * 32 + (lane & 15);
  const int sw0 = (lane >> 4) ^ (lane & 7);
  const bf16x8* pA = (const bf16x8*)sA;
  const bf16x8* pB = (const bf16x8*)sB;

  f32x4 acc[8][4] = {};
  bf16x8 af[4][2], bb[2][2];

  // prologue: tile0 full -> b0 (8 loads); tile1 A0,B0 -> b1 (4 loads)
  STG_A(0, 0, 0); STG_B(0, 0, 0); STG_A(0, 1, 0); STG_B(0, 1, 0);
  STG_A(1, 0, 1); STG_B(1, 0, 1);
  VMC4;  // tile0 landed (only tile1's 4 loads may remain)
  __builtin_amdgcn_s_barrier();

#pragma unroll 1
  for (int i = 0; i < 3; i++) {
    const int t1k = 2 * i + 1;
    const int t2k = 2 * i + 2;
    const int t3k = 2 * i + 3;
    PHASE(0, 0, 0, STG_A(1, 1, t1k), NOPX);
    PHASE(0, 0, 1, STG_B(1, 1, t1k), NOPX);
    PHASE(0, 1, 0, STG_A(0, 0, t2k), NOPX);
    PHASE(0, 1, 1, STG_B(0, 0, t2k), VMC4);
    PHASE(1, 0, 0, STG_A(0, 1, t2k), NOPX);
    PHASE(1, 0, 1, STG_B(0, 1, t2k), NOPX);
    PHASE(1, 1, 0, STG_A(1, 0, t3k), NOPX);
    PHASE(1, 1, 1, STG_B(1, 0, t3k), VMC4);
  }
  // peeled last iteration: tiles 6 (b0), 7 (b1); no further prefetch
  PHASE(0, 0, 0, STG_A(1, 1, 7), NOPX);
  PHASE(0, 0, 1, STG_B(1, 1, 7), NOPX);
  PHASE(0, 1, 0, NOPX, NOPX);
  PHASE(0, 1, 1, NOPX, VMC0);  // tile7 fully landed
  PHASE(1, 0, 0, NOPX, NOPX);
  PHASE(1, 0, 1, NOPX, NOPX);
  PHASE(1, 1, 0, NOPX, NOPX);
  PHASE(1, 1, 1, NOPX, NOPX);

  // epilogue: C/D layout col=lane&15, row=(lane>>4)*4+r
  // acc[f][c] -> row m0+wr*128+f*16+(lane>>4)*4+r,
  //              col n0+wc*32+(c>>1)*128+(c&1)*16+(lane&15)
  const int crow = m0 + wr * 128 + (lane >> 4) * 4;
  const int ccol = n0 + wc * 32 + (lane & 15);
  float* Cp = C + (size_t)crow * 1024 + ccol;
#pragma unroll
  for (int f = 0; f < 8; f++)
#pragma unroll
    for (int r = 0; r < 4; r++)
#pragma unroll
      for (int c = 0; c < 4; c++)
        Cp[(size_t)(f * 16 + r) * 1024 + (c >> 1) * 128 + (c & 1) * 16] =
            acc[f][c][r];
}

// ---------------------------------------------------------------------------
extern "C" void kernel_launch(void* const* d_in, const int* in_sizes, int n_in,
                              void* d_out, int out_size, void* d_ws,
                              size_t ws_size, hipStream_t stream) {
  const float* enc = (const float*)d_in[0];
  const float* dec = (const float*)d_in[1];
  const float* w1  = (const float*)d_in[2];
  const float* b1  = (const float*)d_in[3];
  const float* w2  = (const float*)d_in[4];
  float* out = (float*)d_out;

  unsigned short* bf      = (unsigned short*)d_ws;
  unsigned short* ws_enc  = bf;             // 524288
  unsigned short* ws_dec  = bf + 524288;    // 131072
  unsigned short* ws_wenc = bf + 655360;    // 262144
  unsigned short* ws_wdec = bf + 917504;    // 262144
  unsigned short* ws_w2   = bf + 1179648;   // 524288; end @ 3407872 B
  float* encp = (float*)((char*)d_ws + 3407872);          // 1024x512 f32
  float* decp = encp + 524288;                            // 256x512 f32
  unsigned short* hid = (unsigned short*)(decp + 131072); // 65536x512 bf16

  prep_kernel<<<1664, 256, 0, stream>>>(enc, dec, w1, w2, bf);

  proj_kernel<<<dim3(4, 10), 256, 0, stream>>>(
      (const bf16_t*)ws_enc, (const bf16_t*)ws_wenc, encp,
      (const bf16_t*)ws_dec, (const bf16_t*)ws_wdec, decp);

  hidden_kernel<<<16384, 256, 0, stream>>>(encp, decp, b1, hid);

  gemm_big2<<<1024, 512, 0, stream>>>(
      (const bf16_t*)hid, (const bf16_t*)ws_w2, out);
}